// Round 6
// baseline (235.352 us; speedup 1.0000x reference)
//
#include <hip/hip_runtime.h>
#include <cstddef>
#include <cstdint>

#define EMB 1024
#define NH 16
#define HD 64
#define SEQ 2048
#define BATCH 2
#define MROWS 4096
#define LOG2E 1.4426950408889634f

typedef unsigned short u16;
typedef __attribute__((ext_vector_type(8))) short short8;
typedef __attribute__((ext_vector_type(4))) short short4v;
typedef __attribute__((ext_vector_type(4))) float floatx4;

#define MFMA32(a,b,c) __builtin_amdgcn_mfma_f32_16x16x32_bf16((a),(b),(c),0,0,0)

#if __has_builtin(__builtin_amdgcn_mfma_f32_16x16x16bf16_1k)
#define PVMFMA(a,b,c) __builtin_amdgcn_mfma_f32_16x16x16bf16_1k((a),(b),(c),0,0,0)
#elif __has_builtin(__builtin_amdgcn_mfma_f32_16x16x16_bf16)
#define PVMFMA(a,b,c) __builtin_amdgcn_mfma_f32_16x16x16_bf16((a),(b),(c),0,0,0)
#else
__device__ __forceinline__ floatx4 pv_mfma_fb(short4v a, short4v b, floatx4 c) {
    short8 a8 = {a.x, a.y, a.z, a.w, 0, 0, 0, 0};
    short8 b8 = {b.x, b.y, b.z, b.w, 0, 0, 0, 0};
    return MFMA32(a8, b8, c);
}
#define PVMFMA(a,b,c) pv_mfma_fb((a),(b),(c))
#endif

__device__ __forceinline__ u16 f2bf(float f) {           // RNE
    union { float f; uint32_t u; } v; v.f = f;
    return (u16)((v.u + 0x7fffu + ((v.u >> 16) & 1u)) >> 16);
}
// pack trunc-bf16(a) (lo) | trunc-bf16(b) (hi) in one v_perm
__device__ __forceinline__ uint32_t pk_trunc(float a, float b) {
    union { float f; uint32_t u; } va, vb; va.f = a; vb.f = b;
    return __builtin_amdgcn_perm(vb.u, va.u, 0x07060302u);
}
__device__ __forceinline__ float lo_f(uint32_t u) {
    union { uint32_t u; float f; } v; v.u = u << 16; return v.f;
}
__device__ __forceinline__ float hi_f(uint32_t u) {
    union { uint32_t u; float f; } v; v.u = u & 0xffff0000u; return v.f;
}
typedef const __attribute__((address_space(1))) void* gptr_t;
typedef __attribute__((address_space(3))) void* lptr_t;
__device__ __forceinline__ void gl2lds16(const void* g, void* l) {
    __builtin_amdgcn_global_load_lds((gptr_t)g, (lptr_t)l, 16, 0, 0);
}

// ---------------------------------------------------------------------------
// Fused convert: z<4 -> W[z] fp32 [K][N] -> W^T [N][K] bf16 (z==0 scaled by
// log2e/8); z==4 -> x fp32 -> bf16 (grid-stride over the 4M plane).
// ---------------------------------------------------------------------------
__global__ __launch_bounds__(256) void cvt_all_k(
    const float* __restrict__ x,
    const float* __restrict__ W0, const float* __restrict__ W1,
    const float* __restrict__ W2, const float* __restrict__ W3,
    u16* __restrict__ Wt4, u16* __restrict__ xh) {
    const int z = blockIdx.z;
    const int tid = threadIdx.x;
    if (z == 4) {
        const int nb = gridDim.x * gridDim.y;
        const int bid = blockIdx.y * gridDim.x + blockIdx.x;
        const int stride = nb * 256 * 8;
        for (int i = (bid * 256 + tid) * 8; i < MROWS * EMB; i += stride) {
            float4 a = *(const float4*)(x + i);
            float4 b = *(const float4*)(x + i + 4);
            alignas(16) u16 o[8] = {f2bf(a.x), f2bf(a.y), f2bf(a.z), f2bf(a.w),
                                    f2bf(b.x), f2bf(b.y), f2bf(b.z), f2bf(b.w)};
            *(uint4*)(xh + i) = *(const uint4*)o;
        }
        return;
    }
    const float* W = (z == 0) ? W0 : (z == 1) ? W1 : (z == 2) ? W2 : W3;
    const float scale = (z == 0) ? 0.125f * LOG2E : 1.0f;
    u16* dst = Wt4 + (size_t)z * 1048576;
    __shared__ float Lf[64][65];
    const int kt = blockIdx.y * 64, nt = blockIdx.x * 64;
    {
        const int r = tid >> 2, c4 = (tid & 3) * 16;
        const float* src = W + (size_t)(kt + r) * EMB + nt + c4;
        #pragma unroll
        for (int i = 0; i < 16; i += 4) {
            float4 v = *(const float4*)(src + i);
            Lf[r][c4 + i + 0] = v.x; Lf[r][c4 + i + 1] = v.y;
            Lf[r][c4 + i + 2] = v.z; Lf[r][c4 + i + 3] = v.w;
        }
    }
    __syncthreads();
    const int n = tid >> 2, k4 = (tid & 3) * 16;
    alignas(16) u16 hb[16];
    #pragma unroll
    for (int i = 0; i < 16; ++i) hb[i] = f2bf(Lf[k4 + i][n] * scale);
    const size_t o = (size_t)(nt + n) * EMB + kt + k4;
    *(uint4*)(dst + o) = *(const uint4*)hb;
    *(uint4*)(dst + o + 8) = *(const uint4*)(hb + 8);
}

// ---------------------------------------------------------------------------
// QKV GEMM: 128x128 tile, BK=32, swizzle pos=(c+r+(r>>2))&3. z==2 writes V
// directly transposed to Vt[b][h][d][t] (4 t-consecutive bf16 -> 8B stores).
// ---------------------------------------------------------------------------
__global__ __launch_bounds__(256) void gemm_qkv_k(
    const u16* __restrict__ xh, const u16* __restrict__ Wt4,
    const float* __restrict__ b0, const float* __restrict__ b1,
    const float* __restrict__ b2,
    u16* __restrict__ Q, u16* __restrict__ K, u16* __restrict__ Vt) {
    const int z = blockIdx.z;
    const u16* Wt = Wt4 + (size_t)z * 1048576;
    const float* bias = (z == 0) ? b0 : (z == 1) ? b1 : b2;
    const float bscale = (z == 0) ? 0.125f * LOG2E : 1.0f;
    const int bm = blockIdx.y * 128, bn = blockIdx.x * 128;
    __shared__ alignas(16) u16 As[4096];
    __shared__ alignas(16) u16 Bs[4096];
    const int tid = threadIdx.x;
    const int lane = tid & 63, w = tid >> 6;
    const int l15 = lane & 15, quad = lane >> 4;
    const int wm = (w & 1) * 64, wn = (w >> 1) * 64;

    floatx4 acc[4][4];
    const floatx4 zf = {0.f, 0.f, 0.f, 0.f};
    #pragma unroll
    for (int mt = 0; mt < 4; ++mt)
        #pragma unroll
        for (int nt = 0; nt < 4; ++nt) acc[mt][nt] = zf;

    const int c0 = tid, c1 = tid + 256;
    const int r0 = c0 >> 2, p0 = c0 & 3, cc0 = (p0 - r0 - (r0 >> 2)) & 3;
    const int r1 = c1 >> 2, p1 = c1 & 3, cc1 = (p1 - r1 - (r1 >> 2)) & 3;
    const u16* ag0 = xh + (size_t)(bm + r0) * EMB + cc0 * 8;
    const u16* ag1 = xh + (size_t)(bm + r1) * EMB + cc1 * 8;
    const u16* bg0 = Wt + (size_t)(bn + r0) * EMB + cc0 * 8;
    const u16* bg1 = Wt + (size_t)(bn + r1) * EMB + cc1 * 8;

    for (int kt = 0; kt < EMB; kt += 32) {
        __syncthreads();
        gl2lds16(ag0 + kt, &As[c0 * 8]); gl2lds16(ag1 + kt, &As[c1 * 8]);
        gl2lds16(bg0 + kt, &Bs[c0 * 8]); gl2lds16(bg1 + kt, &Bs[c1 * 8]);
        __syncthreads();
        short8 af[4], bf[4];
        #pragma unroll
        for (int t = 0; t < 4; ++t) {
            const int ra = wm + t * 16 + l15;
            const int rb = wn + t * 16 + l15;
            af[t] = *(const short8*)&As[ra * 32 + ((quad + ra + (ra >> 2)) & 3) * 8];
            bf[t] = *(const short8*)&Bs[rb * 32 + ((quad + rb + (rb >> 2)) & 3) * 8];
        }
        #pragma unroll
        for (int mt = 0; mt < 4; ++mt)
            #pragma unroll
            for (int nt = 0; nt < 4; ++nt)
                acc[mt][nt] = MFMA32(af[mt], bf[nt], acc[mt][nt]);
    }

    if (z != 2) {
        u16* out = (z == 0) ? Q : K;
        #pragma unroll
        for (int nt = 0; nt < 4; ++nt) {
            const int col = bn + wn + nt * 16 + l15;
            const float bv = bias[col] * bscale;
            #pragma unroll
            for (int mt = 0; mt < 4; ++mt) {
                const int row = bm + wm + mt * 16 + quad * 4;
                #pragma unroll
                for (int r = 0; r < 4; ++r)
                    out[(size_t)(row + r) * EMB + col] = f2bf(acc[mt][nt][r] + bv);
            }
        }
    } else {
        #pragma unroll
        for (int nt = 0; nt < 4; ++nt) {
            const int col = bn + wn + nt * 16 + l15;
            const int hh = col >> 6, d = col & 63;
            const float bv = bias[col];
            #pragma unroll
            for (int mt = 0; mt < 4; ++mt) {
                const int row = bm + wm + mt * 16 + quad * 4;
                const int bb = row >> 11, t0 = row & 2047;
                alignas(8) u16 pk4[4];
                #pragma unroll
                for (int r = 0; r < 4; ++r) pk4[r] = f2bf(acc[mt][nt][r] + bv);
                *(uint2*)(Vt + ((size_t)((bb * NH + hh) * HD + d)) * SEQ + t0) =
                    *(const uint2*)pk4;
            }
        }
    }
}

// ---------------------------------------------------------------------------
// O-projection: 128x64 tile, BK=32 -> 512 blocks (2/CU), fp32 out + bias
// ---------------------------------------------------------------------------
__global__ __launch_bounds__(256) void gemm_o_k(
    const u16* __restrict__ Ag, const u16* __restrict__ Wt,
    const float* __restrict__ bias, float* __restrict__ out) {
    const int bm = blockIdx.y * 128, bn = blockIdx.x * 64;
    __shared__ alignas(16) u16 As[4096];   // 128 x 32
    __shared__ alignas(16) u16 Bs[2048];   // 64 x 32
    const int tid = threadIdx.x;
    const int lane = tid & 63, w = tid >> 6;
    const int l15 = lane & 15, quad = lane >> 4;
    const int wm = w * 32;

    floatx4 acc[2][4];
    const floatx4 zf = {0.f, 0.f, 0.f, 0.f};
    #pragma unroll
    for (int mt = 0; mt < 2; ++mt)
        #pragma unroll
        for (int nt = 0; nt < 4; ++nt) acc[mt][nt] = zf;

    const int c0 = tid, c1 = tid + 256;
    const int r0 = c0 >> 2, p0 = c0 & 3, cc0 = (p0 - r0 - (r0 >> 2)) & 3;
    const int r1 = c1 >> 2, p1 = c1 & 3, cc1 = (p1 - r1 - (r1 >> 2)) & 3;
    const u16* ag0 = Ag + (size_t)(bm + r0) * EMB + cc0 * 8;
    const u16* ag1 = Ag + (size_t)(bm + r1) * EMB + cc1 * 8;
    const u16* bg0 = Wt + (size_t)(bn + r0) * EMB + cc0 * 8;   // first 256 slots

    for (int kt = 0; kt < EMB; kt += 32) {
        __syncthreads();
        gl2lds16(ag0 + kt, &As[c0 * 8]);
        gl2lds16(ag1 + kt, &As[c1 * 8]);
        if (c0 < 256) gl2lds16(bg0 + kt, &Bs[c0 * 8]);
        __syncthreads();
        short8 af[2], bf[4];
        #pragma unroll
        for (int t = 0; t < 2; ++t) {
            const int ra = wm + t * 16 + l15;
            af[t] = *(const short8*)&As[ra * 32 + ((quad + ra + (ra >> 2)) & 3) * 8];
        }
        #pragma unroll
        for (int t = 0; t < 4; ++t) {
            const int rb = t * 16 + l15;
            bf[t] = *(const short8*)&Bs[rb * 32 + ((quad + rb + (rb >> 2)) & 3) * 8];
        }
        #pragma unroll
        for (int mt = 0; mt < 2; ++mt)
            #pragma unroll
            for (int nt = 0; nt < 4; ++nt)
                acc[mt][nt] = MFMA32(af[mt], bf[nt], acc[mt][nt]);
    }

    #pragma unroll
    for (int nt = 0; nt < 4; ++nt) {
        const int col = bn + nt * 16 + l15;
        const float bv = bias[col];
        #pragma unroll
        for (int mt = 0; mt < 2; ++mt) {
            const int row = bm + wm + mt * 16 + quad * 4;
            #pragma unroll
            for (int r = 0; r < 4; ++r)
                out[(size_t)(row + r) * EMB + col] = acc[mt][nt][r] + bv;
        }
    }
}

// ---------------------------------------------------------------------------
// Flash attention v6: split-K x4 over t (512 each). Block = (128 q, head,
// b*4+split); 4 waves x 32 q (2x16 tiles sharing each Ks/Vs tile). Grid
// 16x16x8 = 2048 blocks -> 8 blocks/CU, 8192 waves. Fixed-max softmax =>
// numerator & l are plain sums; bf16 N partials + fp32 l, combined by
// reduce_k. Ks/Vs rows swizzled (pos=(c+r)&7), conflict-free-ish.
// ---------------------------------------------------------------------------
__global__ __launch_bounds__(256) void flash_k(
    const u16* __restrict__ Q, const u16* __restrict__ K,
    const u16* __restrict__ Vt,
    u16* __restrict__ Np0, u16* __restrict__ Np1,
    u16* __restrict__ Np2, u16* __restrict__ Np3,
    float* __restrict__ Lp) {
    const int qt = blockIdx.x, h = blockIdx.y;
    const int b = blockIdx.z >> 2, sp = blockIdx.z & 3;
    const int t0 = sp * (SEQ / 4);
    __shared__ alignas(16) u16 Ks[4096];   // [t64][d64] 128B rows, swizzled
    __shared__ alignas(16) u16 Vs[4096];   // [d64][t64] 128B rows, swizzled
    const int tid = threadIdx.x;
    const int lane = tid & 63, w = tid >> 6;
    const int l15 = lane & 15, quad = lane >> 4;

    // Q B-frags for both 16-q tiles: B[k=d=quad*8+j][n=q=l15]
    const u16* qp = Q + (size_t)(b * SEQ + qt * 128 + w * 32 + l15) * EMB + h * HD + quad * 8;
    short8 qb[2][2];
    qb[0][0] = *(const short8*)qp;
    qb[0][1] = *(const short8*)(qp + 32);
    qb[1][0] = *(const short8*)(qp + 16 * EMB);
    qb[1][1] = *(const short8*)(qp + 16 * EMB + 32);

    const floatx4 zf = {0.f, 0.f, 0.f, 0.f};
    floatx4 oacc[2][4];
    float l_part[2] = {0.f, 0.f};
    #pragma unroll
    for (int u = 0; u < 2; ++u)
        #pragma unroll
        for (int nt = 0; nt < 4; ++nt) oacc[u][nt] = zf;

    // staging: slot s -> row r=s>>3, pos p=s&7, source chunk c=(p-r)&7
    const int s0 = tid, s1 = tid + 256;
    const int kr0 = s0 >> 3, kc0 = ((s0 & 7) - kr0) & 7;
    const int kr1 = s1 >> 3, kc1 = ((s1 & 7) - kr1) & 7;
    const u16* kg0 = K + (size_t)(b * SEQ + t0 + kr0) * EMB + h * HD + kc0 * 8;
    const u16* kg1 = K + (size_t)(b * SEQ + t0 + kr1) * EMB + h * HD + kc1 * 8;
    const u16* vg0 = Vt + ((size_t)((b * NH + h) * HD + kr0)) * SEQ + t0 + kc0 * 8;
    const u16* vg1 = Vt + ((size_t)((b * NH + h) * HD + kr1)) * SEQ + t0 + kc1 * 8;

    for (int kt = 0; kt < SEQ / 4 / 64; ++kt) {
        __syncthreads();
        gl2lds16(kg0 + (size_t)kt * 64 * EMB, &Ks[s0 * 8]);
        gl2lds16(kg1 + (size_t)kt * 64 * EMB, &Ks[s1 * 8]);
        gl2lds16(vg0 + kt * 64, &Vs[s0 * 8]);
        gl2lds16(vg1 + kt * 64, &Vs[s1 * 8]);
        __syncthreads();

        // St = K Q^T for both q-tiles; Ks frags shared across u
        floatx4 sa[2][4];
        #pragma unroll
        for (int mt = 0; mt < 4; ++mt) {
            const int r = mt * 16 + l15;
            const short8 ka0 = *(const short8*)&Ks[r * 64 + ((quad + r) & 7) * 8];
            const short8 ka1 = *(const short8*)&Ks[r * 64 + ((quad + 4 + r) & 7) * 8];
            #pragma unroll
            for (int u = 0; u < 2; ++u)
                sa[u][mt] = MFMA32(ka1, qb[u][1], MFMA32(ka0, qb[u][0], zf));
        }

        // exp2 (Q pre-scaled by log2e/8), trunc-pack P, l from rounded P
        short4v pfr[2][4];
        #pragma unroll
        for (int u = 0; u < 2; ++u)
            #pragma unroll
            for (int mt = 0; mt < 4; ++mt) {
                const float e0 = exp2f(sa[u][mt][0]);
                const float e1 = exp2f(sa[u][mt][1]);
                const float e2 = exp2f(sa[u][mt][2]);
                const float e3 = exp2f(sa[u][mt][3]);
                const uint32_t u01 = pk_trunc(e0, e1);
                const uint32_t u23 = pk_trunc(e2, e3);
                l_part[u] += (lo_f(u01) + hi_f(u01)) + (lo_f(u23) + hi_f(u23));
                union { uint32_t uu[2]; short4v s; } pk;
                pk.uu[0] = u01; pk.uu[1] = u23;
                pfr[u][mt] = pk.s;
            }

        // O += P^T V; Vs frags shared across u
        #pragma unroll
        for (int mt = 0; mt < 4; ++mt) {
            const int c16 = mt * 2 + (quad >> 1);
            const int hof = (quad & 1) * 4;
            #pragma unroll
            for (int nt = 0; nt < 4; ++nt) {
                const int vr = nt * 16 + l15;
                const short4v vb =
                    *(const short4v*)&Vs[vr * 64 + ((c16 + vr) & 7) * 8 + hof];
                #pragma unroll
                for (int u = 0; u < 2; ++u)
                    oacc[u][nt] = PVMFMA(pfr[u][mt], vb, oacc[u][nt]);
            }
        }
    }

    u16* np = (sp == 0) ? Np0 : (sp == 1) ? Np1 : (sp == 2) ? Np2 : Np3;
    float* lp = Lp + (size_t)sp * (MROWS * NH);

    // l totals per q=l15 (sum across quads), store once per (u, q)
    #pragma unroll
    for (int u = 0; u < 2; ++u) {
        l_part[u] += __shfl_xor(l_part[u], 16, 64);
        l_part[u] += __shfl_xor(l_part[u], 32, 64);
        if (quad == 0) {
            const int qrow = qt * 128 + w * 32 + u * 16 + l15;
            lp[(size_t)(b * SEQ + qrow) * NH + h] = l_part[u];
        }
    }

    // numerator (unnormalized) C-layout: row=q=quad*4+r, col=d=nt*16+l15
    #pragma unroll
    for (int u = 0; u < 2; ++u)
        #pragma unroll
        for (int r = 0; r < 4; ++r) {
            const size_t o =
                (size_t)(b * SEQ + qt * 128 + w * 32 + u * 16 + quad * 4 + r) * EMB
                + h * HD + l15;
            #pragma unroll
            for (int nt = 0; nt < 4; ++nt)
                np[o + nt * 16] = f2bf(oacc[u][nt][r]);
        }
}

// ---------------------------------------------------------------------------
// Combine 4 split-K partials: AO = (N0+N1+N2+N3)/(l0+l1+l2+l3), bf16 out
// ---------------------------------------------------------------------------
__global__ __launch_bounds__(256) void reduce_k(
    const u16* __restrict__ Np0, const u16* __restrict__ Np1,
    const u16* __restrict__ Np2, const u16* __restrict__ Np3,
    const float* __restrict__ Lp, u16* __restrict__ AO) {
    const int i = blockIdx.x * 256 + threadIdx.x;   // 0 .. 1M-1
    const int e = i * 4;
    const int row = e >> 10;
    const int hh = (e & 1023) >> 6;
    const size_t lx = (size_t)row * NH + hh;
    const float lsum = Lp[lx] + Lp[(size_t)(MROWS * NH) + lx] +
                       Lp[2 * (size_t)(MROWS * NH) + lx] +
                       Lp[3 * (size_t)(MROWS * NH) + lx];
    const float inv = 1.f / lsum;
    const uint2 n0 = *(const uint2*)(Np0 + e);
    const uint2 n1 = *(const uint2*)(Np1 + e);
    const uint2 n2 = *(const uint2*)(Np2 + e);
    const uint2 n3 = *(const uint2*)(Np3 + e);
    const float x0 = (lo_f(n0.x) + lo_f(n1.x) + lo_f(n2.x) + lo_f(n3.x)) * inv;
    const float x1 = (hi_f(n0.x) + hi_f(n1.x) + hi_f(n2.x) + hi_f(n3.x)) * inv;
    const float x2 = (lo_f(n0.y) + lo_f(n1.y) + lo_f(n2.y) + lo_f(n3.y)) * inv;
    const float x3 = (hi_f(n0.y) + hi_f(n1.y) + hi_f(n2.y) + hi_f(n3.y)) * inv;
    uint2 o;
    o.x = (uint32_t)f2bf(x0) | ((uint32_t)f2bf(x1) << 16);
    o.y = (uint32_t)f2bf(x2) | ((uint32_t)f2bf(x3) << 16);
    *(uint2*)(AO + e) = o;
}

// ---------------------------------------------------------------------------
extern "C" void kernel_launch(void* const* d_in, const int* in_sizes, int n_in,
                              void* d_out, int out_size, void* d_ws, size_t ws_size,
                              hipStream_t stream) {
    const float* x  = (const float*)d_in[0];
    const float* Wq = (const float*)d_in[1];
    const float* bq = (const float*)d_in[2];
    const float* Wk = (const float*)d_in[3];
    const float* bk = (const float*)d_in[4];
    const float* Wv = (const float*)d_in[5];
    const float* bv = (const float*)d_in[6];
    const float* Wo = (const float*)d_in[7];
    const float* bo = (const float*)d_in[8];

    u16* ws16 = (u16*)d_ws;
    const size_t P4 = (size_t)MROWS * EMB;   // 4M elems (8 MB)
    u16* xh  = ws16;                 // x bf16; dead after gemm_qkv -> N0
    u16* Qb  = ws16 + P4;            // Q; dead after flash -> AO
    u16* Kb  = ws16 + 2 * P4;
    u16* Vtb = ws16 + 3 * P4;        // V transposed [B][H][D][S]
    u16* Wt4 = ws16 + 4 * P4;        // 4 planes of 1M: Wq^T*log2e/8, Wk^T, Wv^T, Wo^T
    u16* N1  = ws16 + 5 * P4;
    u16* N2  = ws16 + 6 * P4;
    u16* N3  = ws16 + 7 * P4;
    float* Lp = (float*)(ws16 + 8 * P4);   // 4 x 65536 floats (1 MB)

    cvt_all_k<<<dim3(16, 16, 5), 256, 0, stream>>>(x, Wq, Wk, Wv, Wo, Wt4, xh);
    gemm_qkv_k<<<dim3(8, 32, 3), 256, 0, stream>>>(xh, Wt4, bq, bk, bv, Qb, Kb, Vtb);
    flash_k<<<dim3(16, 16, 8), 256, 0, stream>>>(Qb, Kb, Vtb, xh, N1, N2, N3, Lp);
    reduce_k<<<4096, 256, 0, stream>>>(xh, N1, N2, N3, Lp, Qb);
    gemm_o_k<<<dim3(16, 32, 1), 256, 0, stream>>>(Qb, Wt4 + 3 * 1048576, bo, (float*)d_out);
}

// Round 7
// 207.089 us; speedup vs baseline: 1.1365x; 1.1365x over previous
//
#include <hip/hip_runtime.h>
#include <cstddef>
#include <cstdint>

#define EMB 1024
#define NH 16
#define HD 64
#define SEQ 2048
#define BATCH 2
#define MROWS 4096
#define LOG2E 1.4426950408889634f

typedef unsigned short u16;
typedef __attribute__((ext_vector_type(8))) short short8;
typedef __attribute__((ext_vector_type(4))) short short4v;
typedef __attribute__((ext_vector_type(4))) float floatx4;

#define MFMA32(a,b,c) __builtin_amdgcn_mfma_f32_16x16x32_bf16((a),(b),(c),0,0,0)

#if __has_builtin(__builtin_amdgcn_mfma_f32_16x16x16bf16_1k)
#define PVMFMA(a,b,c) __builtin_amdgcn_mfma_f32_16x16x16bf16_1k((a),(b),(c),0,0,0)
#elif __has_builtin(__builtin_amdgcn_mfma_f32_16x16x16_bf16)
#define PVMFMA(a,b,c) __builtin_amdgcn_mfma_f32_16x16x16_bf16((a),(b),(c),0,0,0)
#else
__device__ __forceinline__ floatx4 pv_mfma_fb(short4v a, short4v b, floatx4 c) {
    short8 a8 = {a.x, a.y, a.z, a.w, 0, 0, 0, 0};
    short8 b8 = {b.x, b.y, b.z, b.w, 0, 0, 0, 0};
    return MFMA32(a8, b8, c);
}
#define PVMFMA(a,b,c) pv_mfma_fb((a),(b),(c))
#endif

__device__ __forceinline__ u16 f2bf(float f) {           // RNE
    union { float f; uint32_t u; } v; v.f = f;
    return (u16)((v.u + 0x7fffu + ((v.u >> 16) & 1u)) >> 16);
}
// pack top-16-bits(a) (lo) | top-16-bits(b) (hi) in one v_perm
__device__ __forceinline__ uint32_t pk2u(uint32_t a, uint32_t b) {
    return __builtin_amdgcn_perm(b, a, 0x07060302u);
}
__device__ __forceinline__ float lo_f(uint32_t u) {
    union { uint32_t u; float f; } v; v.u = u << 16; return v.f;
}
__device__ __forceinline__ float hi_f(uint32_t u) {
    union { uint32_t u; float f; } v; v.u = u & 0xffff0000u; return v.f;
}
// Schraudolph 2^s: bits = (int)(s*2^23 + C); max rel err ~3%, cancels via l
__device__ __forceinline__ uint32_t exp2_fast_bits(float s) {
    return (uint32_t)(int)fmaf(s, 8388608.0f, 1064992512.0f);
}
typedef const __attribute__((address_space(1))) void* gptr_t;
typedef __attribute__((address_space(3))) void* lptr_t;
__device__ __forceinline__ void gl2lds16(const void* g, void* l) {
    __builtin_amdgcn_global_load_lds((gptr_t)g, (lptr_t)l, 16, 0, 0);
}

// ---------------------------------------------------------------------------
// Fused convert: z<4 -> W[z] fp32 [K][N] -> W^T [N][K] bf16 (z==0 scaled by
// log2e/8); z==4 -> x fp32 -> bf16 (grid-stride over the 4M plane).
// ---------------------------------------------------------------------------
__global__ __launch_bounds__(256) void cvt_all_k(
    const float* __restrict__ x,
    const float* __restrict__ W0, const float* __restrict__ W1,
    const float* __restrict__ W2, const float* __restrict__ W3,
    u16* __restrict__ Wt4, u16* __restrict__ xh) {
    const int z = blockIdx.z;
    const int tid = threadIdx.x;
    if (z == 4) {
        const int nb = gridDim.x * gridDim.y;
        const int bid = blockIdx.y * gridDim.x + blockIdx.x;
        const int stride = nb * 256 * 8;
        for (int i = (bid * 256 + tid) * 8; i < MROWS * EMB; i += stride) {
            float4 a = *(const float4*)(x + i);
            float4 b = *(const float4*)(x + i + 4);
            alignas(16) u16 o[8] = {f2bf(a.x), f2bf(a.y), f2bf(a.z), f2bf(a.w),
                                    f2bf(b.x), f2bf(b.y), f2bf(b.z), f2bf(b.w)};
            *(uint4*)(xh + i) = *(const uint4*)o;
        }
        return;
    }
    const float* W = (z == 0) ? W0 : (z == 1) ? W1 : (z == 2) ? W2 : W3;
    const float scale = (z == 0) ? 0.125f * LOG2E : 1.0f;
    u16* dst = Wt4 + (size_t)z * 1048576;
    __shared__ float Lf[64][65];
    const int kt = blockIdx.y * 64, nt = blockIdx.x * 64;
    {
        const int r = tid >> 2, c4 = (tid & 3) * 16;
        const float* src = W + (size_t)(kt + r) * EMB + nt + c4;
        #pragma unroll
        for (int i = 0; i < 16; i += 4) {
            float4 v = *(const float4*)(src + i);
            Lf[r][c4 + i + 0] = v.x; Lf[r][c4 + i + 1] = v.y;
            Lf[r][c4 + i + 2] = v.z; Lf[r][c4 + i + 3] = v.w;
        }
    }
    __syncthreads();
    const int n = tid >> 2, k4 = (tid & 3) * 16;
    alignas(16) u16 hb[16];
    #pragma unroll
    for (int i = 0; i < 16; ++i) hb[i] = f2bf(Lf[k4 + i][n] * scale);
    const size_t o = (size_t)(nt + n) * EMB + kt + k4;
    *(uint4*)(dst + o) = *(const uint4*)hb;
    *(uint4*)(dst + o + 8) = *(const uint4*)(hb + 8);
}

// ---------------------------------------------------------------------------
// QKV GEMM (r3/r5 structure): 128x128 tile, BK=32, swizzle pos=(c+r+(r>>2))&3
// All three outputs row-major [B*S][E]; V transposed separately (vtrans_k).
// ---------------------------------------------------------------------------
__global__ __launch_bounds__(256) void gemm_qkv_k(
    const u16* __restrict__ xh, const u16* __restrict__ Wt4,
    const float* __restrict__ b0, const float* __restrict__ b1,
    const float* __restrict__ b2,
    u16* __restrict__ Q, u16* __restrict__ K, u16* __restrict__ V) {
    const int z = blockIdx.z;
    const u16* Wt = Wt4 + (size_t)z * 1048576;
    const float* bias = (z == 0) ? b0 : (z == 1) ? b1 : b2;
    u16* out = (z == 0) ? Q : (z == 1) ? K : V;
    const float bscale = (z == 0) ? 0.125f * LOG2E : 1.0f;
    const int bm = blockIdx.y * 128, bn = blockIdx.x * 128;
    __shared__ alignas(16) u16 As[4096];
    __shared__ alignas(16) u16 Bs[4096];
    const int tid = threadIdx.x;
    const int lane = tid & 63, w = tid >> 6;
    const int l15 = lane & 15, quad = lane >> 4;
    const int wm = (w & 1) * 64, wn = (w >> 1) * 64;

    floatx4 acc[4][4];
    const floatx4 zf = {0.f, 0.f, 0.f, 0.f};
    #pragma unroll
    for (int mt = 0; mt < 4; ++mt)
        #pragma unroll
        for (int nt = 0; nt < 4; ++nt) acc[mt][nt] = zf;

    const int c0 = tid, c1 = tid + 256;
    const int r0 = c0 >> 2, p0 = c0 & 3, cc0 = (p0 - r0 - (r0 >> 2)) & 3;
    const int r1 = c1 >> 2, p1 = c1 & 3, cc1 = (p1 - r1 - (r1 >> 2)) & 3;
    const u16* ag0 = xh + (size_t)(bm + r0) * EMB + cc0 * 8;
    const u16* ag1 = xh + (size_t)(bm + r1) * EMB + cc1 * 8;
    const u16* bg0 = Wt + (size_t)(bn + r0) * EMB + cc0 * 8;
    const u16* bg1 = Wt + (size_t)(bn + r1) * EMB + cc1 * 8;

    for (int kt = 0; kt < EMB; kt += 32) {
        __syncthreads();
        gl2lds16(ag0 + kt, &As[c0 * 8]); gl2lds16(ag1 + kt, &As[c1 * 8]);
        gl2lds16(bg0 + kt, &Bs[c0 * 8]); gl2lds16(bg1 + kt, &Bs[c1 * 8]);
        __syncthreads();
        short8 af[4], bf[4];
        #pragma unroll
        for (int t = 0; t < 4; ++t) {
            const int ra = wm + t * 16 + l15;
            const int rb = wn + t * 16 + l15;
            af[t] = *(const short8*)&As[ra * 32 + ((quad + ra + (ra >> 2)) & 3) * 8];
            bf[t] = *(const short8*)&Bs[rb * 32 + ((quad + rb + (rb >> 2)) & 3) * 8];
        }
        #pragma unroll
        for (int mt = 0; mt < 4; ++mt)
            #pragma unroll
            for (int nt = 0; nt < 4; ++nt)
                acc[mt][nt] = MFMA32(af[mt], bf[nt], acc[mt][nt]);
    }

    #pragma unroll
    for (int nt = 0; nt < 4; ++nt) {
        const int col = bn + wn + nt * 16 + l15;
        const float bv = bias[col] * bscale;
        #pragma unroll
        for (int mt = 0; mt < 4; ++mt) {
            const int row = bm + wm + mt * 16 + quad * 4;
            #pragma unroll
            for (int r = 0; r < 4; ++r)
                out[(size_t)(row + r) * EMB + col] = f2bf(acc[mt][nt][r] + bv);
        }
    }
}

// ---------------------------------------------------------------------------
// O-projection: 128x64 tile, BK=32 -> 512 blocks (2/CU), fp32 out + bias
// ---------------------------------------------------------------------------
__global__ __launch_bounds__(256) void gemm_o_k(
    const u16* __restrict__ Ag, const u16* __restrict__ Wt,
    const float* __restrict__ bias, float* __restrict__ out) {
    const int bm = blockIdx.y * 128, bn = blockIdx.x * 64;
    __shared__ alignas(16) u16 As[4096];   // 128 x 32
    __shared__ alignas(16) u16 Bs[2048];   // 64 x 32
    const int tid = threadIdx.x;
    const int lane = tid & 63, w = tid >> 6;
    const int l15 = lane & 15, quad = lane >> 4;
    const int wm = w * 32;

    floatx4 acc[2][4];
    const floatx4 zf = {0.f, 0.f, 0.f, 0.f};
    #pragma unroll
    for (int mt = 0; mt < 2; ++mt)
        #pragma unroll
        for (int nt = 0; nt < 4; ++nt) acc[mt][nt] = zf;

    const int c0 = tid, c1 = tid + 256;
    const int r0 = c0 >> 2, p0 = c0 & 3, cc0 = (p0 - r0 - (r0 >> 2)) & 3;
    const int r1 = c1 >> 2, p1 = c1 & 3, cc1 = (p1 - r1 - (r1 >> 2)) & 3;
    const u16* ag0 = Ag + (size_t)(bm + r0) * EMB + cc0 * 8;
    const u16* ag1 = Ag + (size_t)(bm + r1) * EMB + cc1 * 8;
    const u16* bg0 = Wt + (size_t)(bn + r0) * EMB + cc0 * 8;   // first 256 slots

    for (int kt = 0; kt < EMB; kt += 32) {
        __syncthreads();
        gl2lds16(ag0 + kt, &As[c0 * 8]);
        gl2lds16(ag1 + kt, &As[c1 * 8]);
        if (c0 < 256) gl2lds16(bg0 + kt, &Bs[c0 * 8]);
        __syncthreads();
        short8 af[2], bf[4];
        #pragma unroll
        for (int t = 0; t < 2; ++t) {
            const int ra = wm + t * 16 + l15;
            af[t] = *(const short8*)&As[ra * 32 + ((quad + ra + (ra >> 2)) & 3) * 8];
        }
        #pragma unroll
        for (int t = 0; t < 4; ++t) {
            const int rb = t * 16 + l15;
            bf[t] = *(const short8*)&Bs[rb * 32 + ((quad + rb + (rb >> 2)) & 3) * 8];
        }
        #pragma unroll
        for (int mt = 0; mt < 2; ++mt)
            #pragma unroll
            for (int nt = 0; nt < 4; ++nt)
                acc[mt][nt] = MFMA32(af[mt], bf[nt], acc[mt][nt]);
    }

    #pragma unroll
    for (int nt = 0; nt < 4; ++nt) {
        const int col = bn + nt * 16 + l15;
        const float bv = bias[col];
        #pragma unroll
        for (int mt = 0; mt < 2; ++mt) {
            const int row = bm + wm + mt * 16 + quad * 4;
            #pragma unroll
            for (int r = 0; r < 4; ++r)
                out[(size_t)(row + r) * EMB + col] = acc[mt][nt][r] + bv;
        }
    }
}

// ---------------------------------------------------------------------------
// V [B*S][E] bf16 -> Vt [B][H][D][S] bf16 (coalesced via LDS)
// ---------------------------------------------------------------------------
__global__ __launch_bounds__(256) void vtrans_k(const u16* __restrict__ V,
                                                u16* __restrict__ Vt) {
    const int tt = blockIdx.x, h = blockIdx.y, b = blockIdx.z;
    __shared__ u16 Lt[64][72];
    const int tid = threadIdx.x;
    {
        const int r = tid >> 2, c4 = (tid & 3) * 16;
        const u16* src = V + (size_t)(b * SEQ + tt * 64 + r) * EMB + h * HD + c4;
        alignas(16) u16 buf[16];
        *(uint4*)buf = *(const uint4*)src;
        *(uint4*)(buf + 8) = *(const uint4*)(src + 8);
        #pragma unroll
        for (int i = 0; i < 16; ++i) Lt[c4 + i][r] = buf[i];
    }
    __syncthreads();
    const int d = tid >> 2, t4 = (tid & 3) * 16;
    u16* dst = Vt + ((size_t)((b * NH + h) * HD + d)) * SEQ + tt * 64 + t4;
    *(uint4*)dst = *(const uint4*)&Lt[d][t4];
    *(uint4*)(dst + 8) = *(const uint4*)&Lt[d][t4 + 8];
}

// ---------------------------------------------------------------------------
// Flash attention v7: split-K x4 over t, 32q/wave. VALU diet:
//  - Schraudolph exp2 (fma+cvt; ~3% rel err, correlated part cancels via l)
//  - l computed by MFMA against a constant ones B-frag, from the SAME
//    truncated P-hat as the numerator (exact bias cancellation, l in-lane)
// Ks/Vs staged via global_load_lds, rows swizzled (pos=(c+r)&7).
// ---------------------------------------------------------------------------
__global__ __launch_bounds__(256) void flash_k(
    const u16* __restrict__ Q, const u16* __restrict__ K,
    const u16* __restrict__ Vt,
    u16* __restrict__ Np0, u16* __restrict__ Np1,
    u16* __restrict__ Np2, u16* __restrict__ Np3,
    float* __restrict__ Lp) {
    const int qt = blockIdx.x, h = blockIdx.y;
    const int b = blockIdx.z >> 2, sp = blockIdx.z & 3;
    const int t0 = sp * (SEQ / 4);
    __shared__ alignas(16) u16 Ks[4096];   // [t64][d64] 128B rows, swizzled
    __shared__ alignas(16) u16 Vs[4096];   // [d64][t64] 128B rows, swizzled
    const int tid = threadIdx.x;
    const int lane = tid & 63, w = tid >> 6;
    const int l15 = lane & 15, quad = lane >> 4;

    // Q B-frags for both 16-q tiles: B[k=d=quad*8+j][n=q=l15]
    const u16* qp = Q + (size_t)(b * SEQ + qt * 128 + w * 32 + l15) * EMB + h * HD + quad * 8;
    short8 qb[2][2];
    qb[0][0] = *(const short8*)qp;
    qb[0][1] = *(const short8*)(qp + 32);
    qb[1][0] = *(const short8*)(qp + 16 * EMB);
    qb[1][1] = *(const short8*)(qp + 16 * EMB + 32);

    const floatx4 zf = {0.f, 0.f, 0.f, 0.f};
    const short4v vones = {0x3F80, 0x3F80, 0x3F80, 0x3F80};   // bf16 1.0 x4
    floatx4 oacc[2][4];
    floatx4 lacc[2];
    #pragma unroll
    for (int u = 0; u < 2; ++u) {
        lacc[u] = zf;
        #pragma unroll
        for (int nt = 0; nt < 4; ++nt) oacc[u][nt] = zf;
    }

    // staging: slot s -> row r=s>>3, pos p=s&7, source chunk c=(p-r)&7
    const int s0 = tid, s1 = tid + 256;
    const int kr0 = s0 >> 3, kc0 = ((s0 & 7) - kr0) & 7;
    const int kr1 = s1 >> 3, kc1 = ((s1 & 7) - kr1) & 7;
    const u16* kg0 = K + (size_t)(b * SEQ + t0 + kr0) * EMB + h * HD + kc0 * 8;
    const u16* kg1 = K + (size_t)(b * SEQ + t0 + kr1) * EMB + h * HD + kc1 * 8;
    const u16* vg0 = Vt + ((size_t)((b * NH + h) * HD + kr0)) * SEQ + t0 + kc0 * 8;
    const u16* vg1 = Vt + ((size_t)((b * NH + h) * HD + kr1)) * SEQ + t0 + kc1 * 8;

    for (int kt = 0; kt < SEQ / 4 / 64; ++kt) {
        __syncthreads();
        gl2lds16(kg0 + (size_t)kt * 64 * EMB, &Ks[s0 * 8]);
        gl2lds16(kg1 + (size_t)kt * 64 * EMB, &Ks[s1 * 8]);
        gl2lds16(vg0 + kt * 64, &Vs[s0 * 8]);
        gl2lds16(vg1 + kt * 64, &Vs[s1 * 8]);
        __syncthreads();

        // St = K Q^T for both q-tiles; Ks frags shared across u
        floatx4 sa[2][4];
        #pragma unroll
        for (int mt = 0; mt < 4; ++mt) {
            const int r = mt * 16 + l15;
            const short8 ka0 = *(const short8*)&Ks[r * 64 + ((quad + r) & 7) * 8];
            const short8 ka1 = *(const short8*)&Ks[r * 64 + ((quad + 4 + r) & 7) * 8];
            #pragma unroll
            for (int u = 0; u < 2; ++u)
                sa[u][mt] = MFMA32(ka1, qb[u][1], MFMA32(ka0, qb[u][0], zf));
        }

        // fast exp2 (Q pre-scaled by log2e/8) -> trunc-packed bf16 P
        short4v pfr[2][4];
        #pragma unroll
        for (int u = 0; u < 2; ++u)
            #pragma unroll
            for (int mt = 0; mt < 4; ++mt) {
                const uint32_t e0 = exp2_fast_bits(sa[u][mt][0]);
                const uint32_t e1 = exp2_fast_bits(sa[u][mt][1]);
                const uint32_t e2 = exp2_fast_bits(sa[u][mt][2]);
                const uint32_t e3 = exp2_fast_bits(sa[u][mt][3]);
                union { uint32_t uu[2]; short4v s; } pk;
                pk.uu[0] = pk2u(e0, e1);
                pk.uu[1] = pk2u(e2, e3);
                pfr[u][mt] = pk.s;
            }

        // O += P^T V (Vs frags shared across u); l += P^T 1 via ones-MFMA
        #pragma unroll
        for (int mt = 0; mt < 4; ++mt) {
            const int c16 = mt * 2 + (quad >> 1);
            const int hof = (quad & 1) * 4;
            #pragma unroll
            for (int nt = 0; nt < 4; ++nt) {
                const int vr = nt * 16 + l15;
                const short4v vb =
                    *(const short4v*)&Vs[vr * 64 + ((c16 + vr) & 7) * 8 + hof];
                #pragma unroll
                for (int u = 0; u < 2; ++u)
                    oacc[u][nt] = PVMFMA(pfr[u][mt], vb, oacc[u][nt]);
            }
            #pragma unroll
            for (int u = 0; u < 2; ++u)
                lacc[u] = PVMFMA(pfr[u][mt], vones, lacc[u]);
        }
    }

    u16* np = (sp == 0) ? Np0 : (sp == 1) ? Np1 : (sp == 2) ? Np2 : Np3;
    float* lp = Lp + (size_t)sp * (MROWS * NH);

    // store l partials (row q = quad*4+r, identical across l15 cols)
    #pragma unroll
    for (int u = 0; u < 2; ++u)
        if (l15 == 0) {
            #pragma unroll
            for (int r = 0; r < 4; ++r) {
                const int qrow = qt * 128 + w * 32 + u * 16 + quad * 4 + r;
                lp[(size_t)(b * SEQ + qrow) * NH + h] = lacc[u][r];
            }
        }

    // numerator (unnormalized) C-layout: row=q=quad*4+r, col=d=nt*16+l15
    #pragma unroll
    for (int u = 0; u < 2; ++u)
        #pragma unroll
        for (int r = 0; r < 4; ++r) {
            const size_t o =
                (size_t)(b * SEQ + qt * 128 + w * 32 + u * 16 + quad * 4 + r) * EMB
                + h * HD + l15;
            #pragma unroll
            for (int nt = 0; nt < 4; ++nt)
                np[o + nt * 16] = f2bf(oacc[u][nt][r]);
        }
}

// ---------------------------------------------------------------------------
// Combine 4 split-K partials: AO = (N0+N1+N2+N3)/(l0+l1+l2+l3), bf16 out
// ---------------------------------------------------------------------------
__global__ __launch_bounds__(256) void reduce_k(
    const u16* __restrict__ Np0, const u16* __restrict__ Np1,
    const u16* __restrict__ Np2, const u16* __restrict__ Np3,
    const float* __restrict__ Lp, u16* __restrict__ AO) {
    const int i = blockIdx.x * 256 + threadIdx.x;   // 0 .. 1M-1
    const int e = i * 4;
    const int row = e >> 10;
    const int hh = (e & 1023) >> 6;
    const size_t lx = (size_t)row * NH + hh;
    const float lsum = Lp[lx] + Lp[(size_t)(MROWS * NH) + lx] +
                       Lp[2 * (size_t)(MROWS * NH) + lx] +
                       Lp[3 * (size_t)(MROWS * NH) + lx];
    const float inv = 1.f / lsum;
    const uint2 n0 = *(const uint2*)(Np0 + e);
    const uint2 n1 = *(const uint2*)(Np1 + e);
    const uint2 n2 = *(const uint2*)(Np2 + e);
    const uint2 n3 = *(const uint2*)(Np3 + e);
    const float x0 = (lo_f(n0.x) + lo_f(n1.x) + lo_f(n2.x) + lo_f(n3.x)) * inv;
    const float x1 = (hi_f(n0.x) + hi_f(n1.x) + hi_f(n2.x) + hi_f(n3.x)) * inv;
    const float x2 = (lo_f(n0.y) + lo_f(n1.y) + lo_f(n2.y) + lo_f(n3.y)) * inv;
    const float x3 = (hi_f(n0.y) + hi_f(n1.y) + hi_f(n2.y) + hi_f(n3.y)) * inv;
    uint2 o;
    o.x = (uint32_t)f2bf(x0) | ((uint32_t)f2bf(x1) << 16);
    o.y = (uint32_t)f2bf(x2) | ((uint32_t)f2bf(x3) << 16);
    *(uint2*)(AO + e) = o;
}

// ---------------------------------------------------------------------------
extern "C" void kernel_launch(void* const* d_in, const int* in_sizes, int n_in,
                              void* d_out, int out_size, void* d_ws, size_t ws_size,
                              hipStream_t stream) {
    const float* x  = (const float*)d_in[0];
    const float* Wq = (const float*)d_in[1];
    const float* bq = (const float*)d_in[2];
    const float* Wk = (const float*)d_in[3];
    const float* bk = (const float*)d_in[4];
    const float* Wv = (const float*)d_in[5];
    const float* bv = (const float*)d_in[6];
    const float* Wo = (const float*)d_in[7];
    const float* bo = (const float*)d_in[8];

    u16* ws16 = (u16*)d_ws;
    const size_t P4 = (size_t)MROWS * EMB;   // 4M elems (8 MB)
    u16* xh  = ws16;                 // x bf16; dead after gemm_qkv -> N0
    u16* Qb  = ws16 + P4;            // Q; dead after flash -> AO
    u16* Kb  = ws16 + 2 * P4;
    u16* Vb  = ws16 + 3 * P4;        // V row-major; dead after vtrans -> N1
    u16* Vtb = ws16 + 4 * P4;        // V transposed [B][H][D][S]
    u16* Wt4 = ws16 + 5 * P4;        // 4 planes of 1M: Wq^T*log2e/8, Wk^T, Wv^T, Wo^T
    u16* N2  = ws16 + 6 * P4;
    u16* N3  = ws16 + 7 * P4;
    float* Lp = (float*)(ws16 + 8 * P4);   // 4 x 65536 floats (1 MB)

    cvt_all_k<<<dim3(16, 16, 5), 256, 0, stream>>>(x, Wq, Wk, Wv, Wo, Wt4, xh);
    gemm_qkv_k<<<dim3(8, 32, 3), 256, 0, stream>>>(xh, Wt4, bq, bk, bv, Qb, Kb, Vb);
    vtrans_k<<<dim3(32, 16, 2), 256, 0, stream>>>(Vb, Vtb);
    flash_k<<<dim3(16, 16, 8), 256, 0, stream>>>(Qb, Kb, Vtb, xh, Vb, N2, N3, Lp);
    reduce_k<<<4096, 256, 0, stream>>>(xh, Vb, N2, N3, Lp, Qb);
    gemm_o_k<<<dim3(16, 32, 1), 256, 0, stream>>>(Qb, Wt4 + 3 * 1048576, bo, (float*)d_out);
}